// Round 2
// baseline (116.538 us; speedup 1.0000x reference)
//
#include <hip/hip_runtime.h>
#include <cstdint>

#define BB   16
#define NN   1024
#define FIN  128
#define FOUT 64
#define ALPHA_S 0.2f
#define LOG2E 1.44269504f

typedef float    f32x4 __attribute__((ext_vector_type(4)));
typedef _Float16 half8 __attribute__((ext_vector_type(8)));
typedef _Float16 half4 __attribute__((ext_vector_type(4)));
typedef __fp16   pk2   __attribute__((ext_vector_type(2)));
typedef __fp16   pk4   __attribute__((ext_vector_type(4)));
typedef __fp16   pk8   __attribute__((ext_vector_type(8)));

__device__ __forceinline__ float fast_exp2(float x){
  float r; asm("v_exp_f32 %0, %1" : "=v"(r) : "v"(x)); return r;
}

// ---------------------------------------------------------------------------
// Kernel 1 (MFMA): h = inp @ W via f16 hi/lo 3-term MFMA (rel err ~2^-22);
// s1 = (h.a1)*log2e, s2 = (h.a2)*log2e  (log2-domain fold for k_attn's exp2);
// hT (f16, hi only) in layout hT[b][j>>5][f][j&31].
// ---------------------------------------------------------------------------
__global__ __launch_bounds__(256) void k_proj(const float* __restrict__ inp,
                                              const float* __restrict__ W,
                                              const float* __restrict__ a,
                                              _Float16* __restrict__ hT,
                                              float* __restrict__ s1,
                                              float* __restrict__ s2){
  __shared__ float red1[4][16];
  __shared__ float red2[4][16];
  const int t = threadIdx.x;
  const int w = t >> 6, lane = t & 63;
  const int m16 = lane & 15, g = lane >> 4;
  const int i0 = blockIdx.x * 16;          // global row tile (16 rows)
  const int b  = i0 >> 10;
  const int j0 = i0 & 1023;
  const int c0 = w * 16;                   // this wave's col tile

  const float* arow = inp + (size_t)(i0 + m16) * FIN;

  f32x4 acc = {0.f, 0.f, 0.f, 0.f};
  #pragma unroll
  for (int kk = 0; kk < 4; ++kk){
    const int kbase = kk * 32 + g * 8;
    float4 av0 = *(const float4*)(arow + kbase);
    float4 av1 = *(const float4*)(arow + kbase + 4);
    const float av[8] = {av0.x, av0.y, av0.z, av0.w, av1.x, av1.y, av1.z, av1.w};
    half8 ah, al;
    #pragma unroll
    for (int j = 0; j < 8; ++j){
      _Float16 h = (_Float16)av[j];
      ah[j] = h;
      al[j] = (_Float16)(av[j] - (float)h);
    }
    half8 bh, bl;
    #pragma unroll
    for (int j = 0; j < 8; ++j){
      float wv = W[(kbase + j) * FOUT + c0 + m16];   // L1-hot (W = 32 KB)
      _Float16 h = (_Float16)wv;
      bh[j] = h;
      bl[j] = (_Float16)(wv - (float)h);
    }
    acc = __builtin_amdgcn_mfma_f32_16x16x32_f16(ah, bh, acc, 0, 0, 0);
    acc = __builtin_amdgcn_mfma_f32_16x16x32_f16(ah, bl, acc, 0, 0, 0);
    acc = __builtin_amdgcn_mfma_f32_16x16x32_f16(al, bh, acc, 0, 0, 0);
  }

  // ---- s1/s2 partials: sum over this wave's 16 cols, rows g*4+q ----
  const float a1c = a[c0 + m16];
  const float a2c = a[FOUT + c0 + m16];
  f32x4 p1, p2;
  #pragma unroll
  for (int q = 0; q < 4; ++q){ p1[q] = acc[q] * a1c; p2[q] = acc[q] * a2c; }
  #pragma unroll
  for (int off = 1; off < 16; off <<= 1){
    #pragma unroll
    for (int q = 0; q < 4; ++q){
      p1[q] += __shfl_xor(p1[q], off, 64);
      p2[q] += __shfl_xor(p2[q], off, 64);
    }
  }
  if (m16 == 0){
    #pragma unroll
    for (int q = 0; q < 4; ++q){
      red1[w][g * 4 + q] = p1[q];
      red2[w][g * 4 + q] = p2[q];
    }
  }

  // ---- hT store (hi only): f = c0+m16, j = i0 + g*4 + q ----
  half4 hv;
  #pragma unroll
  for (int q = 0; q < 4; ++q) hv[q] = (_Float16)acc[q];
  size_t idx = (size_t)b * 65536 + (size_t)(j0 >> 5) * 2048
             + (size_t)(c0 + m16) * 32 + (size_t)(j0 & 31) + (size_t)g * 4;
  *(half4*)(hT + idx) = hv;

  __syncthreads();
  if (t < 16){
    s1[i0 + t] = (red1[0][t] + red1[1][t] + red1[2][t] + red1[3][t]) * LOG2E;
    s2[i0 + t] = (red2[0][t] + red2[1][t] + red2[2][t] + red2[3][t]) * LOG2E;
  }
}

// ---------------------------------------------------------------------------
// Kernel 2: fused GAT attention, barrier-free main body.
// 1024 blocks x 256 thr. Block = (batch, 16-row tile). Wave w owns j-range
// [w*256, w*256+256).  Pass 1: adj burst-load -> pre-masked scores
// sm[64] = adj ? s2L : -3e38 in registers + wave-LOCAL masked row max.
// Pass 2: p = exp2(max(s1m+sm, fma(a,sm,c2)))  (log2 domain; -inf masks
// propagate to p=0), f16 A-frags via v_cvt_pkrtz, 4 MFMA C tiles.
// Single barrier; epilogue rescales each wave's acc/psum by
// exp2(m_w - m_global)  (exact flash-style cross-wave softmax merge).
// ---------------------------------------------------------------------------
__global__ __launch_bounds__(256) void k_attn(const int* __restrict__ adj,
                                              const _Float16* __restrict__ hT,
                                              const float* __restrict__ s1,
                                              const float* __restrict__ s2,
                                              float* __restrict__ out){
  __shared__ float s2_s[NN];            // 4 KB
  __shared__ float redmax[4][16];
  __shared__ float redl[4][16];
  __shared__ float csum[4][1088];       // 4 x (16 rows x 68-pad) ~17 KB

  const int t = threadIdx.x;
  const int w = t >> 6, lane = t & 63;
  const int m16 = lane & 15, g = lane >> 4;
  const int b  = blockIdx.x >> 6;
  const int i0 = (blockIdx.x & 63) * 16;
  const int jb = w * 256;

  // stage this wave's s2L chunk FIRST (oldest vmem op -> ds_write only
  // waits for it, not for the adj burst; wave-internal lgkmcnt ordering)
  *(float4*)&s2_s[jb + lane * 4] = *(const float4*)(s2 + b * NN + jb + lane * 4);

  // ---- adj burst: 16 int4 loads in flight; row i0+m16, cols jb+kk*32+g*8 ----
  const int* arow = adj + ((size_t)(b * NN + i0 + m16)) * NN + jb + g * 8;
  int4 A0[8], A1[8];
  #pragma unroll
  for (int kk = 0; kk < 8; ++kk){
    A0[kk] = *(const int4*)(arow + kk * 32);
    A1[kk] = *(const int4*)(arow + kk * 32 + 4);
  }

  const float s1i = s1[b * NN + i0 + m16];

  // ---- pass 1: pre-masked scores in regs + wave-local masked row max ----
  float sm[64];
  float mxp = -3.0e38f;
  #pragma unroll
  for (int kk = 0; kk < 8; ++kk){
    float4 sA = *(const float4*)&s2_s[jb + kk * 32 + g * 8];
    float4 sB = *(const float4*)&s2_s[jb + kk * 32 + g * 8 + 4];
    float v;
    v = (A0[kk].x > 0) ? sA.x : -3.0e38f; sm[kk*8+0] = v; mxp = fmaxf(mxp, v);
    v = (A0[kk].y > 0) ? sA.y : -3.0e38f; sm[kk*8+1] = v; mxp = fmaxf(mxp, v);
    v = (A0[kk].z > 0) ? sA.z : -3.0e38f; sm[kk*8+2] = v; mxp = fmaxf(mxp, v);
    v = (A0[kk].w > 0) ? sA.w : -3.0e38f; sm[kk*8+3] = v; mxp = fmaxf(mxp, v);
    v = (A1[kk].x > 0) ? sB.x : -3.0e38f; sm[kk*8+4] = v; mxp = fmaxf(mxp, v);
    v = (A1[kk].y > 0) ? sB.y : -3.0e38f; sm[kk*8+5] = v; mxp = fmaxf(mxp, v);
    v = (A1[kk].z > 0) ? sB.z : -3.0e38f; sm[kk*8+6] = v; mxp = fmaxf(mxp, v);
    v = (A1[kk].w > 0) ? sB.w : -3.0e38f; sm[kk*8+7] = v; mxp = fmaxf(mxp, v);
  }

  // wave-local row max across the 4 lanes sharing m16 (no cross-wave barrier)
  mxp = fmaxf(mxp, __shfl_xor(mxp, 16, 64));
  mxp = fmaxf(mxp, __shfl_xor(mxp, 32, 64));
  mxp = fmaxf(mxp, -1.0e30f);                 // empty-row safe clamp
  const float xm   = s1i + mxp;
  const float mrow = fmaxf(xm, ALPHA_S * xm); // wave-local max of leaky (log2 dom)
  if (g == 0) redmax[w][m16] = mrow;
  const float s1m = s1i - mrow;
  const float c2  = ALPHA_S * s1i - mrow;

  // ---- pass 2: p in A-frag layout -> 4 col-tile MFMAs (hi only) ----
  f32x4 acc0 = {0,0,0,0}, acc1 = {0,0,0,0}, acc2 = {0,0,0,0}, acc3 = {0,0,0,0};
  float psA = 0.f, psB = 0.f;
  const size_t bbase = (size_t)b * 65536 + (size_t)(w * 8) * 2048
                     + (size_t)m16 * 32 + (size_t)g * 8;
  const _Float16* bhp = hT + bbase;

  #pragma unroll
  for (int kk = 0; kk < 8; ++kk){
    float p0 = fast_exp2(fmaxf(s1m + sm[kk*8+0], fmaf(ALPHA_S, sm[kk*8+0], c2)));
    float p1 = fast_exp2(fmaxf(s1m + sm[kk*8+1], fmaf(ALPHA_S, sm[kk*8+1], c2)));
    float p2 = fast_exp2(fmaxf(s1m + sm[kk*8+2], fmaf(ALPHA_S, sm[kk*8+2], c2)));
    float p3 = fast_exp2(fmaxf(s1m + sm[kk*8+3], fmaf(ALPHA_S, sm[kk*8+3], c2)));
    float p4 = fast_exp2(fmaxf(s1m + sm[kk*8+4], fmaf(ALPHA_S, sm[kk*8+4], c2)));
    float p5 = fast_exp2(fmaxf(s1m + sm[kk*8+5], fmaf(ALPHA_S, sm[kk*8+5], c2)));
    float p6 = fast_exp2(fmaxf(s1m + sm[kk*8+6], fmaf(ALPHA_S, sm[kk*8+6], c2)));
    float p7 = fast_exp2(fmaxf(s1m + sm[kk*8+7], fmaf(ALPHA_S, sm[kk*8+7], c2)));
    psA += (p0 + p1) + (p2 + p3);
    psB += (p4 + p5) + (p6 + p7);
    pk2 q0 = __builtin_amdgcn_cvt_pkrtz(p0, p1);
    pk2 q1 = __builtin_amdgcn_cvt_pkrtz(p2, p3);
    pk2 q2 = __builtin_amdgcn_cvt_pkrtz(p4, p5);
    pk2 q3 = __builtin_amdgcn_cvt_pkrtz(p6, p7);
    pk4 l0 = __builtin_shufflevector(q0, q1, 0, 1, 2, 3);
    pk4 l1 = __builtin_shufflevector(q2, q3, 0, 1, 2, 3);
    pk8 afp = __builtin_shufflevector(l0, l1, 0, 1, 2, 3, 4, 5, 6, 7);
    half8 af = __builtin_bit_cast(half8, afp);
    half8 b0 = *(const half8*)(bhp + kk * 2048);
    half8 b1 = *(const half8*)(bhp + kk * 2048 + 512);
    half8 b2 = *(const half8*)(bhp + kk * 2048 + 1024);
    half8 b3 = *(const half8*)(bhp + kk * 2048 + 1536);
    acc0 = __builtin_amdgcn_mfma_f32_16x16x32_f16(af, b0, acc0, 0, 0, 0);
    acc1 = __builtin_amdgcn_mfma_f32_16x16x32_f16(af, b1, acc1, 0, 0, 0);
    acc2 = __builtin_amdgcn_mfma_f32_16x16x32_f16(af, b2, acc2, 0, 0, 0);
    acc3 = __builtin_amdgcn_mfma_f32_16x16x32_f16(af, b3, acc3, 0, 0, 0);
  }

  // ---- epilogue: single barrier; flash-style cross-wave merge ----
  float psum = psA + psB;
  psum += __shfl_xor(psum, 16, 64);
  psum += __shfl_xor(psum, 32, 64);
  if (g == 0) redl[w][m16] = psum;

  #pragma unroll
  for (int q = 0; q < 4; ++q){                 // C: row = g*4+q, col = c*16+m16
    csum[w][(g * 4 + q) * 68 +  0 + m16] = acc0[q];
    csum[w][(g * 4 + q) * 68 + 16 + m16] = acc1[q];
    csum[w][(g * 4 + q) * 68 + 32 + m16] = acc2[q];
    csum[w][(g * 4 + q) * 68 + 48 + m16] = acc3[q];
  }
  __syncthreads();

  const int r  = t >> 4;                       // 0..15
  const int c4 = (t & 15) * 4;                 // 0..60
  const float m0 = redmax[0][r], m1 = redmax[1][r];
  const float m2 = redmax[2][r], m3 = redmax[3][r];
  const float mg = fmaxf(fmaxf(m0, m1), fmaxf(m2, m3));
  const float f0 = fast_exp2(m0 - mg), f1 = fast_exp2(m1 - mg);
  const float f2 = fast_exp2(m2 - mg), f3 = fast_exp2(m3 - mg);

  f32x4 c0v = *(const f32x4*)&csum[0][r * 68 + c4];
  f32x4 c1v = *(const f32x4*)&csum[1][r * 68 + c4];
  f32x4 c2v = *(const f32x4*)&csum[2][r * 68 + c4];
  f32x4 c3v = *(const f32x4*)&csum[3][r * 68 + c4];
  f32x4 sum;
  #pragma unroll
  for (int u = 0; u < 4; ++u)
    sum[u] = c0v[u] * f0 + c1v[u] * f1 + c2v[u] * f2 + c3v[u] * f3;

  const float l = redl[0][r] * f0 + redl[1][r] * f1
                + redl[2][r] * f2 + redl[3][r] * f3;
  const float linv = (l > 0.f) ? __builtin_amdgcn_rcpf(l) : 0.f;
  f32x4 o;
  #pragma unroll
  for (int u = 0; u < 4; ++u){
    float v = sum[u] * linv;
    o[u] = v > 0.f ? v : __expf(v) - 1.0f;     // ELU (alpha=1)
  }
  *(f32x4*)(out + ((size_t)(b * NN + i0 + r)) * FOUT + c4) = o;
}

extern "C" void kernel_launch(void* const* d_in, const int* in_sizes, int n_in,
                              void* d_out, int out_size, void* d_ws, size_t ws_size,
                              hipStream_t stream) {
  (void)in_sizes; (void)n_in; (void)out_size; (void)ws_size;
  const float* inp = (const float*)d_in[0];   // (16,1024,128) fp32
  const int*   adj = (const int*)d_in[1];     // (16,1024,1024) int32
  const float* W   = (const float*)d_in[2];   // (128,64) fp32
  const float* a   = (const float*)d_in[3];   // (128,1) fp32
  float* outp = (float*)d_out;                // (16,1024,64) fp32

  _Float16* hT = (_Float16*)d_ws;                      // 2 MB (hi only)
  float* s1 = (float*)(hT + (size_t)BB * 65536);       // 64 KB
  float* s2 = s1 + BB * NN;                            // 64 KB

  k_proj<<<BB * NN / 16, 256, 0, stream>>>(inp, W, a, hT, s1, s2);
  k_attn<<<BB * (NN / 16), 256, 0, stream>>>(adj, hT, s1, s2, outp);
}